// Round 1
// baseline (901.525 us; speedup 1.0000x reference)
//
#include <hip/hip_runtime.h>
#include <hip/hip_bf16.h>

// Problem constants
#define BATCH 32
#define CIN   1024
#define HW    784     // 28*28
#define WIMG  28
#define PADW  30      // padded 30x30 plane
#define PADHW 900
#define P1    256
#define P2    256
#define P3    1024
#define ASTR  40      // LDS row stride in bf16 units (32 + 8 pad, keeps 16B align)

typedef __attribute__((ext_vector_type(8))) short bfrag_t;          // 8 bf16 in 4 VGPRs (guide-verified)
typedef __attribute__((ext_vector_type(8))) unsigned short usvec8;
typedef __attribute__((ext_vector_type(4))) float accvec_t;

static __device__ __forceinline__ unsigned short f2bf(float f) {
    union { __hip_bfloat16 h; unsigned short u; } cv;
    cv.h = __float2bfloat16(f);
    return cv.u;
}

// inv[c][perm[c][q]] = q   (so scatter target of conv1 output (c,q) is inv[c][q]... see epilogue)
__global__ __launch_bounds__(256) void build_inv_kernel(const int* __restrict__ perm,
                                                        int* __restrict__ inv) {
    int i = blockIdx.x * 256 + threadIdx.x;   // i < P1*HW exactly (784 blocks)
    int c = i / HW;
    int q = i - c * HW;
    inv[c * HW + perm[i]] = q;
}

// ---------------- conv1: Y1sp[b][pos][c] = scatter(relu(W1 x X_b)) ----------------
__global__ __launch_bounds__(256) void conv1_kernel(const float* __restrict__ x,
                                                    const float* __restrict__ w1,
                                                    const int* __restrict__ inv,
                                                    unsigned short* __restrict__ y1sp) {
    __shared__ __align__(16) unsigned short As[64 * ASTR];
    __shared__ __align__(16) unsigned short Bs[64 * ASTR];
    const int m0 = blockIdx.x * 64;
    const int n0 = blockIdx.y * 64;
    const int b  = blockIdx.z;
    const int t  = threadIdx.x;
    const int lane = t & 63, wave = t >> 6;
    const int l15 = lane & 15, quad = lane >> 4;
    // A staging map: thread -> (row m, k-group of 8)
    const int am = t >> 2, akg = (t & 3) << 3;
    // B staging map: thread -> (k row, n-group of 8)  [transpose into Bs[n][k]]
    const int bkk = t >> 3, bng = (t & 7) << 3;
    const int bn = n0 + bng;
    const bool bvalid = bn < HW;   // 784 % 8 == 0 -> whole groups in/out
    const float* Xb = x + (size_t)b * (CIN * HW);

    accvec_t acc[4];
    accvec_t zero = {0.f, 0.f, 0.f, 0.f};
#pragma unroll
    for (int i = 0; i < 4; ++i) acc[i] = zero;

    for (int k0 = 0; k0 < CIN; k0 += 32) {
        // --- stage A tile (64 x 32): w1 row-major, K contiguous
        const float* ap = w1 + (size_t)(m0 + am) * CIN + k0 + akg;
        float4 a0 = *(const float4*)ap;
        float4 a1 = *(const float4*)(ap + 4);
        usvec8 av;
        av[0] = f2bf(a0.x); av[1] = f2bf(a0.y); av[2] = f2bf(a0.z); av[3] = f2bf(a0.w);
        av[4] = f2bf(a1.x); av[5] = f2bf(a1.y); av[6] = f2bf(a1.z); av[7] = f2bf(a1.w);
        *(usvec8*)&As[am * ASTR + akg] = av;
        // --- stage B tile transposed (Bs[n][k]): X[k][n], n contiguous
        if (bvalid) {
            const float* bp = Xb + (size_t)(k0 + bkk) * HW + bn;
            float4 b0 = *(const float4*)bp;
            float4 b1 = *(const float4*)(bp + 4);
            Bs[(bng + 0) * ASTR + bkk] = f2bf(b0.x);
            Bs[(bng + 1) * ASTR + bkk] = f2bf(b0.y);
            Bs[(bng + 2) * ASTR + bkk] = f2bf(b0.z);
            Bs[(bng + 3) * ASTR + bkk] = f2bf(b0.w);
            Bs[(bng + 4) * ASTR + bkk] = f2bf(b1.x);
            Bs[(bng + 5) * ASTR + bkk] = f2bf(b1.y);
            Bs[(bng + 6) * ASTR + bkk] = f2bf(b1.z);
            Bs[(bng + 7) * ASTR + bkk] = f2bf(b1.w);
        } else {
#pragma unroll
            for (int j = 0; j < 8; ++j) Bs[(bng + j) * ASTR + bkk] = 0;
        }
        __syncthreads();
        bfrag_t a = *(const bfrag_t*)&As[(wave * 16 + l15) * ASTR + (quad << 3)];
#pragma unroll
        for (int tt = 0; tt < 4; ++tt) {
            bfrag_t bb = *(const bfrag_t*)&Bs[(tt * 16 + l15) * ASTR + (quad << 3)];
            acc[tt] = __builtin_amdgcn_mfma_f32_16x16x32_bf16(a, bb, acc[tt], 0, 0, 0);
        }
        __syncthreads();
    }
    // epilogue: relu + scatter through inv into padded channel-inner layout
#pragma unroll
    for (int tt = 0; tt < 4; ++tt) {
        const int n = n0 + tt * 16 + l15;
        if (n < HW) {
#pragma unroll
            for (int r = 0; r < 4; ++r) {
                const int m = m0 + wave * 16 + quad * 4 + r;
                float v = acc[tt][r];
                v = v > 0.f ? v : 0.f;
                const int p  = inv[m * HW + n];           // Y1s[b][m][p] = Y1[b][m][n]
                const int ph = p / WIMG;
                const int pw = p - ph * WIMG;
                const int pos = (ph + 1) * PADW + pw + 1;
                y1sp[((size_t)b * PADHW + pos) * P1 + m] = f2bf(v);
            }
        }
    }
}

// ---------------- dconv: Y2t[b][hw][p2] = relu(conv3x3(Y1sp, wd)) ----------------
__global__ __launch_bounds__(256) void dconv_kernel(const unsigned short* __restrict__ y1sp,
                                                    const float* __restrict__ wd,
                                                    unsigned short* __restrict__ y2t) {
    __shared__ __align__(16) unsigned short As[64 * ASTR];
    __shared__ __align__(16) unsigned short Bs[64 * ASTR];
    const int m0 = blockIdx.x * 64;
    const int n0 = blockIdx.y * 64;
    const int b  = blockIdx.z;
    const int t  = threadIdx.x;
    const int lane = t & 63, wave = t >> 6;
    const int l15 = lane & 15, quad = lane >> 4;
    const int am = t >> 2, akg = (t & 3) << 3;
    const int bnn = t >> 2, bkg = (t & 3) << 3;
    const int bn = n0 + bnn;
    const bool bvalid = bn < HW;
    const int h = bn / WIMG;
    const int w = bn - h * WIMG;
    const unsigned short* Yb = y1sp + (size_t)b * PADHW * P1;

    accvec_t acc[4];
    accvec_t zero = {0.f, 0.f, 0.f, 0.f};
#pragma unroll
    for (int i = 0; i < 4; ++i) acc[i] = zero;
    const usvec8 zb = {0, 0, 0, 0, 0, 0, 0, 0};

    for (int r = 0; r < 9; ++r) {
        const int kh = r / 3;
        const int kw = r - kh * 3;
        const int pos = (h + kh) * PADW + (w + kw);   // padded coords; border = zeros
        const unsigned short* bsrc = Yb + (size_t)pos * P1 + bkg;
        for (int k0 = 0; k0 < P1; k0 += 32) {
            // A: wd[m][k0+kk][kh][kw] -> stride-9 gather
            const float* ap = wd + (size_t)(m0 + am) * (P1 * 9) + (size_t)(k0 + akg) * 9 + r;
            usvec8 av;
#pragma unroll
            for (int j = 0; j < 8; ++j) av[j] = f2bf(ap[9 * j]);
            *(usvec8*)&As[am * ASTR + akg] = av;
            // B: channel-inner padded plane -> contiguous 16B
            usvec8 bv = zb;
            if (bvalid) bv = *(const usvec8*)(bsrc + k0);
            *(usvec8*)&Bs[bnn * ASTR + bkg] = bv;
            __syncthreads();
            bfrag_t a = *(const bfrag_t*)&As[(wave * 16 + l15) * ASTR + (quad << 3)];
#pragma unroll
            for (int tt = 0; tt < 4; ++tt) {
                bfrag_t bb = *(const bfrag_t*)&Bs[(tt * 16 + l15) * ASTR + (quad << 3)];
                acc[tt] = __builtin_amdgcn_mfma_f32_16x16x32_bf16(a, bb, acc[tt], 0, 0, 0);
            }
            __syncthreads();
        }
    }
#pragma unroll
    for (int tt = 0; tt < 4; ++tt) {
        const int n = n0 + tt * 16 + l15;
        if (n < HW) {
#pragma unroll
            for (int r = 0; r < 4; ++r) {
                const int m = m0 + wave * 16 + quad * 4 + r;
                float v = acc[tt][r];
                v = v > 0.f ? v : 0.f;
                y2t[((size_t)b * HW + n) * P2 + m] = f2bf(v);
            }
        }
    }
}

// ---------------- conv3 + shuffled residual + relu ----------------
__global__ __launch_bounds__(256) void conv3_kernel(const unsigned short* __restrict__ y2t,
                                                    const float* __restrict__ w3,
                                                    const float* __restrict__ x,
                                                    const int* __restrict__ perm_res,
                                                    float* __restrict__ out) {
    __shared__ __align__(16) unsigned short As[64 * ASTR];
    __shared__ __align__(16) unsigned short Bs[64 * ASTR];
    const int m0 = blockIdx.x * 64;
    const int n0 = blockIdx.y * 64;
    const int b  = blockIdx.z;
    const int t  = threadIdx.x;
    const int lane = t & 63, wave = t >> 6;
    const int l15 = lane & 15, quad = lane >> 4;
    const int am = t >> 2, akg = (t & 3) << 3;
    const int bnn = t >> 2, bkg = (t & 3) << 3;
    const int bn = n0 + bnn;
    const bool bvalid = bn < HW;
    const unsigned short* Yb = y2t + (size_t)b * HW * P2;

    accvec_t acc[4];
    accvec_t zero = {0.f, 0.f, 0.f, 0.f};
#pragma unroll
    for (int i = 0; i < 4; ++i) acc[i] = zero;
    const usvec8 zb = {0, 0, 0, 0, 0, 0, 0, 0};

    for (int k0 = 0; k0 < P2; k0 += 32) {
        const float* ap = w3 + (size_t)(m0 + am) * P2 + k0 + akg;
        float4 a0 = *(const float4*)ap;
        float4 a1 = *(const float4*)(ap + 4);
        usvec8 av;
        av[0] = f2bf(a0.x); av[1] = f2bf(a0.y); av[2] = f2bf(a0.z); av[3] = f2bf(a0.w);
        av[4] = f2bf(a1.x); av[5] = f2bf(a1.y); av[6] = f2bf(a1.z); av[7] = f2bf(a1.w);
        *(usvec8*)&As[am * ASTR + akg] = av;
        usvec8 bv = zb;
        if (bvalid) bv = *(const usvec8*)(Yb + (size_t)bn * P2 + k0 + bkg);
        *(usvec8*)&Bs[bnn * ASTR + bkg] = bv;
        __syncthreads();
        bfrag_t a = *(const bfrag_t*)&As[(wave * 16 + l15) * ASTR + (quad << 3)];
#pragma unroll
        for (int tt = 0; tt < 4; ++tt) {
            bfrag_t bb = *(const bfrag_t*)&Bs[(tt * 16 + l15) * ASTR + (quad << 3)];
            acc[tt] = __builtin_amdgcn_mfma_f32_16x16x32_bf16(a, bb, acc[tt], 0, 0, 0);
        }
        __syncthreads();
    }
#pragma unroll
    for (int tt = 0; tt < 4; ++tt) {
        const int n = n0 + tt * 16 + l15;
        if (n < HW) {
#pragma unroll
            for (int r = 0; r < 4; ++r) {
                const int m = m0 + wave * 16 + quad * 4 + r;
                const int p = perm_res[m * HW + n];
                const float res = x[((size_t)b * P3 + m) * HW + p];
                float v = acc[tt][r] + res;
                v = v > 0.f ? v : 0.f;
                out[((size_t)b * P3 + m) * HW + n] = v;
            }
        }
    }
}

extern "C" void kernel_launch(void* const* d_in, const int* in_sizes, int n_in,
                              void* d_out, int out_size, void* d_ws, size_t ws_size,
                              hipStream_t stream) {
    const float* x        = (const float*)d_in[0];
    const float* w1       = (const float*)d_in[1];
    const float* wd       = (const float*)d_in[2];
    const float* w3       = (const float*)d_in[3];
    const int*   perm_d   = (const int*)d_in[4];
    const int*   perm_r   = (const int*)d_in[5];
    float*       out      = (float*)d_out;

    char* ws = (char*)d_ws;
    int* inv = (int*)ws;                                            //   802,816 B
    unsigned short* y1sp = (unsigned short*)(ws + 802816);          // 14,745,600 B
    unsigned short* y2t  = (unsigned short*)(ws + 802816 + 14745600); // 12,845,056 B

    // zero padded shuffled-activation buffer (borders must be 0; interior is overwritten)
    hipMemsetAsync(y1sp, 0, (size_t)BATCH * PADHW * P1 * sizeof(unsigned short), stream);
    build_inv_kernel<<<dim3(HW), dim3(256), 0, stream>>>(perm_d, inv);
    conv1_kernel<<<dim3(P1 / 64, 13, BATCH), dim3(256), 0, stream>>>(x, w1, inv, y1sp);
    dconv_kernel<<<dim3(P2 / 64, 13, BATCH), dim3(256), 0, stream>>>(y1sp, wd, y2t);
    conv3_kernel<<<dim3(P3 / 64, 13, BATCH), dim3(256), 0, stream>>>(y2t, w3, x, perm_r, out);
}

// Round 2
// 477.501 us; speedup vs baseline: 1.8880x; 1.8880x over previous
//
#include <hip/hip_runtime.h>
#include <hip/hip_bf16.h>

// Problem constants
#define BATCH 32
#define CIN   1024
#define HW    784     // 28*28
#define WIMG  28
#define PADW  30      // padded 30x30 plane
#define PADHW 900
#define P1    256
#define P2    256
#define P3    1024
#define NFLAT (BATCH * HW)   // 25088 = 196 * 128 exactly

typedef __attribute__((ext_vector_type(8))) short bfrag_t;   // 8 bf16 (4 VGPRs)
typedef __attribute__((ext_vector_type(4))) float accvec_t;  // 4 fp32 acc

static __device__ __forceinline__ unsigned short f2bf(float f) {
    union { __hip_bfloat16 h; unsigned short u; } cv;
    cv.h = __float2bfloat16(f);
    return cv.u;
}

// async 16B global->LDS (direct-to-shared DMA). LDS dest is wave-uniform base
// + lane*16B; global src is per-lane.
#define GLDS16(g, l) __builtin_amdgcn_global_load_lds(                      \
        (const __attribute__((address_space(1))) void*)(g),                 \
        (__attribute__((address_space(3))) void*)(l), 16, 0, 0)

// ---------------- pre-pass: inverse shuffle permutation ----------------
__global__ __launch_bounds__(256) void build_inv_kernel(const int* __restrict__ perm,
                                                        int* __restrict__ inv) {
    int i = blockIdx.x * 256 + threadIdx.x;   // i < P1*HW exactly
    int c = i / HW;
    inv[c * HW + perm[i]] = i - c * HW;
}

// ---------------- pre-pass: pack weights to bf16 ----------------
// w1b[m][k] = bf16(w1[m][k]); w3b same; wdb[r][m][k] = bf16(wd[m][k][r])
__global__ __launch_bounds__(256) void pack_weights_kernel(
        const float* __restrict__ w1, const float* __restrict__ wd,
        const float* __restrict__ w3, unsigned short* __restrict__ w1b,
        unsigned short* __restrict__ wdb, unsigned short* __restrict__ w3b) {
    int i = blockIdx.x * 256 + threadIdx.x;
    if (i < 262144) w1b[i] = f2bf(w1[i]);
    int i2 = i - 262144;
    if (i2 >= 0 && i2 < 262144) w3b[i2] = f2bf(w3[i2]);
    int i3 = i - 524288;
    if (i3 >= 0 && i3 < 589824) {
        int m = i3 / 2304, rem = i3 - m * 2304;
        int k = rem / 9, r = rem - k * 9;
        wdb[((size_t)r * P2 + m) * P1 + k] = f2bf(wd[i3]);
    }
}

// ---------------- pre-pass: transpose x -> xt[b*HW+hw][c] bf16 ----------------
__global__ __launch_bounds__(256) void transpose_x_kernel(const float* __restrict__ x,
                                                          unsigned short* __restrict__ xt) {
    __shared__ unsigned short T[64 * 66];   // stride 66: conflict-free both phases
    const int b   = blockIdx.z;
    const int c0  = blockIdx.x * 64;
    const int hw0 = blockIdx.y * 64;
    const int t = threadIdx.x;
    const int j = t & 63, i0 = t >> 6;
    const float* xb = x + ((size_t)b * CIN + c0) * HW + hw0;
    const bool jv = (hw0 + j) < HW;
#pragma unroll
    for (int ii = 0; ii < 16; ++ii) {
        int i = i0 * 16 + ii;                       // channel row
        float v = jv ? xb[(size_t)i * HW + j] : 0.f;
        T[i * 66 + j] = f2bf(v);
    }
    __syncthreads();
#pragma unroll
    for (int ii = 0; ii < 16; ++ii) {
        int rr = i0 * 16 + ii;                      // spatial row
        if (hw0 + rr < HW)
            xt[((size_t)b * HW + hw0 + rr) * CIN + c0 + j] = T[j * 66 + rr];
    }
}

// ======================================================================
// m97-style 128x128 GEMM structure: 4 waves (2x2), acc[4][4] of 16x16x32,
// BK=32, async global_load_lds staging. LDS tiles [128 rows][32 k] unpadded.
// ======================================================================

// ---------------- conv1: Y1sp[b][pos][c] = scatter(relu(W1 x X)) ----------------
__global__ __launch_bounds__(256) void conv1_kernel(const unsigned short* __restrict__ xt,
                                                    const unsigned short* __restrict__ w1b,
                                                    const int* __restrict__ inv,
                                                    unsigned short* __restrict__ y1sp) {
    __shared__ __align__(16) unsigned short As[128 * 32];
    __shared__ __align__(16) unsigned short Bs[128 * 32];
    const int m0 = blockIdx.x * 128;
    const int n0 = blockIdx.y * 128;       // flattened b*HW + hw
    const int t = threadIdx.x;
    const int lane = t & 63, wave = t >> 6;
    const int l15 = lane & 15, quad = lane >> 4;
    const int wm = wave & 1, wn = wave >> 1;
    const int srow = lane >> 2, c8 = (lane & 3) << 3;
    const int row0 = wave * 32 + srow, row1 = row0 + 16;

    const unsigned short* a0 = w1b + (size_t)(m0 + row0) * CIN + c8;
    const unsigned short* a1 = w1b + (size_t)(m0 + row1) * CIN + c8;
    const unsigned short* b0 = xt + (size_t)(n0 + row0) * CIN + c8;
    const unsigned short* b1 = xt + (size_t)(n0 + row1) * CIN + c8;
    unsigned short* Ad0 = &As[(wave * 2 + 0) * 512];
    unsigned short* Ad1 = &As[(wave * 2 + 1) * 512];
    unsigned short* Bd0 = &Bs[(wave * 2 + 0) * 512];
    unsigned short* Bd1 = &Bs[(wave * 2 + 1) * 512];

    accvec_t acc[4][4];
    const accvec_t zero = {0.f, 0.f, 0.f, 0.f};
#pragma unroll
    for (int i = 0; i < 4; ++i)
#pragma unroll
        for (int j = 0; j < 4; ++j) acc[i][j] = zero;

    for (int k0 = 0; k0 < CIN; k0 += 32) {
        GLDS16(a0 + k0, Ad0);
        GLDS16(a1 + k0, Ad1);
        GLDS16(b0 + k0, Bd0);
        GLDS16(b1 + k0, Bd1);
        __syncthreads();
        bfrag_t af[4], bfr[4];
#pragma unroll
        for (int i = 0; i < 4; ++i) {
            af[i]  = *(const bfrag_t*)&As[(wm * 64 + i * 16 + l15) * 32 + (quad << 3)];
            bfr[i] = *(const bfrag_t*)&Bs[(wn * 64 + i * 16 + l15) * 32 + (quad << 3)];
        }
#pragma unroll
        for (int im = 0; im < 4; ++im)
#pragma unroll
            for (int in = 0; in < 4; ++in)
                acc[im][in] = __builtin_amdgcn_mfma_f32_16x16x32_bf16(af[im], bfr[in], acc[im][in], 0, 0, 0);
        __syncthreads();
    }
    // epilogue: relu + scatter through inv into padded channel-inner layout
#pragma unroll
    for (int in = 0; in < 4; ++in) {
        const int n = n0 + wn * 64 + in * 16 + l15;
        const int b = n / HW, hw = n - b * HW;
#pragma unroll
        for (int im = 0; im < 4; ++im) {
#pragma unroll
            for (int r = 0; r < 4; ++r) {
                const int m = m0 + wm * 64 + im * 16 + (quad << 2) + r;
                float v = acc[im][in][r];
                v = v > 0.f ? v : 0.f;
                const int p  = inv[m * HW + hw];
                const int ph = p / WIMG, pw = p - ph * WIMG;
                y1sp[((size_t)b * PADHW + (ph + 1) * PADW + pw + 1) * P1 + m] = f2bf(v);
            }
        }
    }
}

// ---------------- dconv: Y2t[b*HW+hw][p2] = relu(conv3x3(Y1sp, wdb)) ----------------
__global__ __launch_bounds__(256) void dconv_kernel(const unsigned short* __restrict__ y1sp,
                                                    const unsigned short* __restrict__ wdb,
                                                    unsigned short* __restrict__ y2t) {
    __shared__ __align__(16) unsigned short As[128 * 32];
    __shared__ __align__(16) unsigned short Bs[128 * 32];
    const int m0 = blockIdx.x * 128;
    const int n0 = blockIdx.y * 128;
    const int t = threadIdx.x;
    const int lane = t & 63, wave = t >> 6;
    const int l15 = lane & 15, quad = lane >> 4;
    const int wm = wave & 1, wn = wave >> 1;
    const int srow = lane >> 2, c8 = (lane & 3) << 3;
    const int row0 = wave * 32 + srow, row1 = row0 + 16;

    // decompose this thread's two B-rows (flattened n) once
    const int nj0 = n0 + row0, nj1 = n0 + row1;
    const int bb0 = nj0 / HW, hwj0 = nj0 - bb0 * HW, h0 = hwj0 / WIMG, w0 = hwj0 - h0 * WIMG;
    const int bb1 = nj1 / HW, hwj1 = nj1 - bb1 * HW, h1 = hwj1 / WIMG, w1_ = hwj1 - h1 * WIMG;
    const unsigned short* Yb0 = y1sp + (size_t)bb0 * PADHW * P1 + c8;
    const unsigned short* Yb1 = y1sp + (size_t)bb1 * PADHW * P1 + c8;
    const unsigned short* A0 = wdb + (size_t)(m0 + row0) * P1 + c8;
    const unsigned short* A1 = wdb + (size_t)(m0 + row1) * P1 + c8;
    unsigned short* Ad0 = &As[(wave * 2 + 0) * 512];
    unsigned short* Ad1 = &As[(wave * 2 + 1) * 512];
    unsigned short* Bd0 = &Bs[(wave * 2 + 0) * 512];
    unsigned short* Bd1 = &Bs[(wave * 2 + 1) * 512];

    accvec_t acc[4][4];
    const accvec_t zero = {0.f, 0.f, 0.f, 0.f};
#pragma unroll
    for (int i = 0; i < 4; ++i)
#pragma unroll
        for (int j = 0; j < 4; ++j) acc[i][j] = zero;

    for (int r = 0; r < 9; ++r) {
        const int kh = r / 3, kw = r - kh * 3;
        const unsigned short* as0 = A0 + (size_t)r * (P1 * P2);
        const unsigned short* as1 = A1 + (size_t)r * (P1 * P2);
        const unsigned short* bs0 = Yb0 + (size_t)((h0 + kh) * PADW + w0 + kw) * P1;
        const unsigned short* bs1 = Yb1 + (size_t)((h1 + kh) * PADW + w1_ + kw) * P1;
        for (int k0 = 0; k0 < P1; k0 += 32) {
            GLDS16(as0 + k0, Ad0);
            GLDS16(as1 + k0, Ad1);
            GLDS16(bs0 + k0, Bd0);
            GLDS16(bs1 + k0, Bd1);
            __syncthreads();
            bfrag_t af[4], bfr[4];
#pragma unroll
            for (int i = 0; i < 4; ++i) {
                af[i]  = *(const bfrag_t*)&As[(wm * 64 + i * 16 + l15) * 32 + (quad << 3)];
                bfr[i] = *(const bfrag_t*)&Bs[(wn * 64 + i * 16 + l15) * 32 + (quad << 3)];
            }
#pragma unroll
            for (int im = 0; im < 4; ++im)
#pragma unroll
                for (int in = 0; in < 4; ++in)
                    acc[im][in] = __builtin_amdgcn_mfma_f32_16x16x32_bf16(af[im], bfr[in], acc[im][in], 0, 0, 0);
            __syncthreads();
        }
    }
#pragma unroll
    for (int in = 0; in < 4; ++in) {
        const int n = n0 + wn * 64 + in * 16 + l15;
#pragma unroll
        for (int im = 0; im < 4; ++im) {
#pragma unroll
            for (int r = 0; r < 4; ++r) {
                const int m = m0 + wm * 64 + im * 16 + (quad << 2) + r;
                float v = acc[im][in][r];
                v = v > 0.f ? v : 0.f;
                y2t[(size_t)n * P2 + m] = f2bf(v);
            }
        }
    }
}

// ---------------- conv3 + shuffled residual + relu ----------------
__global__ __launch_bounds__(256) void conv3_kernel(const unsigned short* __restrict__ y2t,
                                                    const unsigned short* __restrict__ w3b,
                                                    const float* __restrict__ x,
                                                    const int* __restrict__ perm_res,
                                                    float* __restrict__ out) {
    __shared__ __align__(16) unsigned short As[128 * 32];
    __shared__ __align__(16) unsigned short Bs[128 * 32];
    const int m0 = blockIdx.x * 128;
    const int n0 = blockIdx.y * 128;
    const int t = threadIdx.x;
    const int lane = t & 63, wave = t >> 6;
    const int l15 = lane & 15, quad = lane >> 4;
    const int wm = wave & 1, wn = wave >> 1;
    const int srow = lane >> 2, c8 = (lane & 3) << 3;
    const int row0 = wave * 32 + srow, row1 = row0 + 16;

    const unsigned short* a0 = w3b + (size_t)(m0 + row0) * P2 + c8;
    const unsigned short* a1 = w3b + (size_t)(m0 + row1) * P2 + c8;
    const unsigned short* b0 = y2t + (size_t)(n0 + row0) * P2 + c8;
    const unsigned short* b1 = y2t + (size_t)(n0 + row1) * P2 + c8;
    unsigned short* Ad0 = &As[(wave * 2 + 0) * 512];
    unsigned short* Ad1 = &As[(wave * 2 + 1) * 512];
    unsigned short* Bd0 = &Bs[(wave * 2 + 0) * 512];
    unsigned short* Bd1 = &Bs[(wave * 2 + 1) * 512];

    accvec_t acc[4][4];
    const accvec_t zero = {0.f, 0.f, 0.f, 0.f};
#pragma unroll
    for (int i = 0; i < 4; ++i)
#pragma unroll
        for (int j = 0; j < 4; ++j) acc[i][j] = zero;

    for (int k0 = 0; k0 < P2; k0 += 32) {
        GLDS16(a0 + k0, Ad0);
        GLDS16(a1 + k0, Ad1);
        GLDS16(b0 + k0, Bd0);
        GLDS16(b1 + k0, Bd1);
        __syncthreads();
        bfrag_t af[4], bfr[4];
#pragma unroll
        for (int i = 0; i < 4; ++i) {
            af[i]  = *(const bfrag_t*)&As[(wm * 64 + i * 16 + l15) * 32 + (quad << 3)];
            bfr[i] = *(const bfrag_t*)&Bs[(wn * 64 + i * 16 + l15) * 32 + (quad << 3)];
        }
#pragma unroll
        for (int im = 0; im < 4; ++im)
#pragma unroll
            for (int in = 0; in < 4; ++in)
                acc[im][in] = __builtin_amdgcn_mfma_f32_16x16x32_bf16(af[im], bfr[in], acc[im][in], 0, 0, 0);
        __syncthreads();
    }
#pragma unroll
    for (int in = 0; in < 4; ++in) {
        const int n = n0 + wn * 64 + in * 16 + l15;
        const int b = n / HW, hw = n - b * HW;
#pragma unroll
        for (int im = 0; im < 4; ++im) {
#pragma unroll
            for (int r = 0; r < 4; ++r) {
                const int m = m0 + wm * 64 + im * 16 + (quad << 2) + r;
                const int p = perm_res[m * HW + hw];
                const float res = x[((size_t)b * P3 + m) * HW + p];
                float v = acc[im][in][r] + res;
                v = v > 0.f ? v : 0.f;
                out[((size_t)b * P3 + m) * HW + hw] = v;
            }
        }
    }
}

extern "C" void kernel_launch(void* const* d_in, const int* in_sizes, int n_in,
                              void* d_out, int out_size, void* d_ws, size_t ws_size,
                              hipStream_t stream) {
    const float* x      = (const float*)d_in[0];
    const float* w1     = (const float*)d_in[1];
    const float* wd     = (const float*)d_in[2];
    const float* w3     = (const float*)d_in[3];
    const int*   perm_d = (const int*)d_in[4];
    const int*   perm_r = (const int*)d_in[5];
    float*       out    = (float*)d_out;

    char* ws = (char*)d_ws;
    int*            inv  = (int*)(ws + 0);                    //    802,816 B
    unsigned short* y1sp = (unsigned short*)(ws + 802816);    // 14,745,600 B
    unsigned short* y2t  = (unsigned short*)(ws + 15548416);  // 12,845,056 B
    unsigned short* xt   = (unsigned short*)(ws + 28393472);  // 51,380,224 B
    unsigned short* w1b  = (unsigned short*)(ws + 79773696);  //    524,288 B
    unsigned short* wdb  = (unsigned short*)(ws + 80297984);  //  1,179,648 B
    unsigned short* w3b  = (unsigned short*)(ws + 81477632);  //    524,288 B

    // borders of padded shuffled-activation buffer must be zero
    hipMemsetAsync(y1sp, 0, (size_t)BATCH * PADHW * P1 * sizeof(unsigned short), stream);
    build_inv_kernel<<<dim3(HW), dim3(256), 0, stream>>>(perm_d, inv);
    pack_weights_kernel<<<dim3(4352), dim3(256), 0, stream>>>(w1, wd, w3, w1b, wdb, w3b);
    transpose_x_kernel<<<dim3(16, 13, BATCH), dim3(256), 0, stream>>>(x, xt);

    conv1_kernel<<<dim3(P1 / 128, NFLAT / 128), dim3(256), 0, stream>>>(xt, w1b, inv, y1sp);
    dconv_kernel<<<dim3(P2 / 128, NFLAT / 128), dim3(256), 0, stream>>>(y1sp, wdb, y2t);
    conv3_kernel<<<dim3(P3 / 128, NFLAT / 128), dim3(256), 0, stream>>>(y2t, w3b, x, perm_r, out);
}

// Round 3
// 395.417 us; speedup vs baseline: 2.2799x; 1.2076x over previous
//
#include <hip/hip_runtime.h>
#include <hip/hip_bf16.h>

// Problem constants
#define BATCH 32
#define CIN   1024
#define HW    784     // 28*28
#define WIMG  28
#define PADW  30      // padded 30x30 plane
#define PADHW 900
#define P1    256
#define P2    256
#define P3    1024
#define NFLAT (BATCH * HW)   // 25088 = 196 * 128 exactly

typedef __attribute__((ext_vector_type(8))) short bfrag_t;          // 8 bf16 (4 VGPRs)
typedef __attribute__((ext_vector_type(8))) unsigned short usvec8;
typedef __attribute__((ext_vector_type(4))) float accvec_t;

static __device__ __forceinline__ unsigned short f2bf(float f) {
    union { __hip_bfloat16 h; unsigned short u; } cv;
    cv.h = __float2bfloat16(f);
    return cv.u;
}
static __device__ __forceinline__ float bf2f(unsigned short u) {
    union { float f; unsigned int i; } cv;
    cv.i = ((unsigned int)u) << 16;
    return cv.f;
}

// async 16B global->LDS DMA. LDS dest is wave-uniform base + lane*16B.
#define GLDS16(g, l) __builtin_amdgcn_global_load_lds(                      \
        (const __attribute__((address_space(1))) void*)(g),                 \
        (__attribute__((address_space(3))) void*)(l), 16, 0, 0)

// ---------------- pre-pass: transpose perm_dconv -> permT[p][c] ----------------
__global__ __launch_bounds__(256) void permT_kernel(const int* __restrict__ perm,
                                                    int* __restrict__ permT) {
    int p = blockIdx.x, c = threadIdx.x;
    permT[p * P1 + c] = perm[c * HW + p];
}

// ---------------- pre-pass: pack weights to bf16 ----------------
// w1b[m][k]; w3b[m][k]; wdb[r][m][k] = bf16(wd[m][k][r])
__global__ __launch_bounds__(256) void pack_weights_kernel(
        const float* __restrict__ w1, const float* __restrict__ wd,
        const float* __restrict__ w3, unsigned short* __restrict__ w1b,
        unsigned short* __restrict__ wdb, unsigned short* __restrict__ w3b) {
    int i = blockIdx.x * 256 + threadIdx.x;
    if (i < 262144) w1b[i] = f2bf(w1[i]);
    int i2 = i - 262144;
    if (i2 >= 0 && i2 < 262144) w3b[i2] = f2bf(w3[i2]);
    int i3 = i - 524288;
    if (i3 >= 0 && i3 < 589824) {
        int m = i3 / 2304, rem = i3 - m * 2304;
        int k = rem / 9, r = rem - k * 9;
        wdb[((size_t)r * P2 + m) * P1 + k] = f2bf(wd[i3]);
    }
}

// ---------------- pre-pass: transpose x -> xt[b*HW+hw][c] bf16 ----------------
__global__ __launch_bounds__(256) void transpose_x_kernel(const float* __restrict__ x,
                                                          unsigned short* __restrict__ xt) {
    __shared__ unsigned short T[64 * 66];
    const int b   = blockIdx.z;
    const int c0  = blockIdx.x * 64;
    const int hw0 = blockIdx.y * 64;
    const int t = threadIdx.x;
    const int j = t & 63, i0 = t >> 6;
    const float* xb = x + ((size_t)b * CIN + c0) * HW + hw0;
    const bool jv = (hw0 + j) < HW;
#pragma unroll
    for (int ii = 0; ii < 16; ++ii) {
        int i = i0 * 16 + ii;
        float v = jv ? xb[(size_t)i * HW + j] : 0.f;
        T[i * 66 + j] = f2bf(v);
    }
    __syncthreads();
#pragma unroll
    for (int ii = 0; ii < 16; ++ii) {
        int rr = i0 * 16 + ii;
        if (hw0 + rr < HW)
            xt[((size_t)b * HW + hw0 + rr) * CIN + c0 + j] = T[j * 66 + rr];
    }
}

// ---------------- residual shuffle via LDS: res[b][c][hw] = bf16(x[b][c][perm_res[c][hw]]) ----
__global__ __launch_bounds__(256) void res_shuffle_kernel(const float* __restrict__ x,
                                                          const int* __restrict__ perm_res,
                                                          unsigned short* __restrict__ res) {
    __shared__ float Lx[8 * 788];     // 8 rows, stride 788 (16B-aligned)
    const int g0 = blockIdx.x * 8;    // 8 (b,c) rows per block
    const int t = threadIdx.x;
    // phase 1: coalesced float4 loads of 8 rows (x flat index = g*784)
#pragma unroll
    for (int it = 0; it < 7; ++it) {
        int chunk = it * 256 + t;
        if (chunk < 1568) {
            int r = chunk / 196, off = (chunk - r * 196) * 4;
            float4 v = *(const float4*)&x[(size_t)(g0 + r) * HW + off];
            *(float4*)&Lx[r * 788 + off] = v;
        }
    }
    __syncthreads();
    // phase 2: gather from LDS, coalesced bf16 stores
    const int q0 = t & 63;
#pragma unroll
    for (int rp = 0; rp < 2; ++rp) {
        int r = rp * 4 + (t >> 6);
        int g = g0 + r;
        int m = g & (CIN - 1);
        const int* pr = perm_res + (size_t)m * HW;
#pragma unroll
        for (int it = 0; it < 13; ++it) {
            int q = it * 64 + q0;
            if (q < HW) {
                int pv = pr[q];
                res[(size_t)g * HW + q] = f2bf(Lx[r * 788 + pv]);
            }
        }
    }
}

// ---------------- shuffle+pad via LDS: y1sp[b][pos][c] from y1c[b][c][hw] ----------------
__global__ __launch_bounds__(256) void shuffle_pad_kernel(const unsigned short* __restrict__ y1c,
                                                          const int* __restrict__ permT,
                                                          unsigned short* __restrict__ y1sp) {
    __shared__ unsigned short Ly[32 * 800];   // 32 channels x plane, stride 800 (16B-aligned)
    const int b  = blockIdx.x >> 3;
    const int c0 = (blockIdx.x & 7) * 32;
    const int t = threadIdx.x;
    // phase 1: coalesced 16B loads of 32 channel rows
#pragma unroll
    for (int it = 0; it < 13; ++it) {
        int chunk = it * 256 + t;
        if (chunk < 3136) {
            int c = chunk / 98, off8 = (chunk - c * 98) * 8;
            usvec8 v = *(const usvec8*)&y1c[((size_t)(b * P1 + c0 + c)) * HW + off8];
            *(usvec8*)&Ly[c * 800 + off8] = v;
        }
    }
    __syncthreads();
    // phase 2: per output pos, gather per-channel source, write 64B channel segments
    const int pc = t & 31, pi = t >> 5;   // 32 channels x 8 positions
    unsigned short* yb = y1sp + (size_t)b * PADHW * P1 + c0 + pc;
#pragma unroll 4
    for (int it = 0; it < 98; ++it) {
        int p = it * 8 + pi;
        int pv = permT[p * P1 + c0 + pc];
        unsigned short val = Ly[pc * 800 + pv];
        int ph = p / WIMG, pw = p - ph * WIMG;
        yb[(size_t)((ph + 1) * PADW + pw + 1) * P1] = val;
    }
}

// ======================================================================
// GEMMs: 128x128 tile, 4 waves (2x2), BK=64 with XOR chunk swizzle,
// async global_load_lds (16B). LDS row = 64 ushorts (128B), contiguous.
// ======================================================================

// ---------------- conv1: y1c[b][m][hw] = relu(W1 x X) ----------------
__global__ __launch_bounds__(256) void conv1_kernel(const unsigned short* __restrict__ xt,
                                                    const unsigned short* __restrict__ w1b,
                                                    unsigned short* __restrict__ y1c) {
    __shared__ __align__(16) unsigned short As[128 * 64];
    __shared__ __align__(16) unsigned short Bs[128 * 64];
    const int m0 = blockIdx.x * 128;
    const int n0 = blockIdx.y * 128;
    const int t = threadIdx.x;
    const int lane = t & 63, wave = t >> 6;
    const int l15 = lane & 15, quad = lane >> 4;
    const int wm = wave & 1, wn = wave >> 1;
    // staging: per wave 4 issues x (8 rows x 128B)
    const int grow = lane >> 3;
    const int gsw  = ((lane & 7) ^ grow) << 3;     // swizzled k-chunk (ushort offset)
    const unsigned short* Asrc[4];
    const unsigned short* Bsrc[4];
    int ldso[4];
#pragma unroll
    for (int j = 0; j < 4; ++j) {
        int q = wave * 4 + j;
        int row = (q << 3) + grow;
        Asrc[j] = w1b + (size_t)(m0 + row) * CIN + gsw;
        Bsrc[j] = xt + (size_t)(n0 + row) * CIN + gsw;
        ldso[j] = q * 512;
    }
    const int coff0 = ((quad)     ^ (l15 & 7)) << 3;
    const int coff1 = ((quad + 4) ^ (l15 & 7)) << 3;

    accvec_t acc[4][4];
    const accvec_t zero = {0.f, 0.f, 0.f, 0.f};
#pragma unroll
    for (int i = 0; i < 4; ++i)
#pragma unroll
        for (int j = 0; j < 4; ++j) acc[i][j] = zero;

    for (int k0 = 0; k0 < CIN; k0 += 64) {
#pragma unroll
        for (int j = 0; j < 4; ++j) {
            GLDS16(Asrc[j] + k0, &As[ldso[j]]);
            GLDS16(Bsrc[j] + k0, &Bs[ldso[j]]);
        }
        __syncthreads();
        bfrag_t af[4], bfr[4];
#pragma unroll
        for (int i = 0; i < 4; ++i) {
            af[i]  = *(const bfrag_t*)&As[(wm * 64 + i * 16 + l15) * 64 + coff0];
            bfr[i] = *(const bfrag_t*)&Bs[(wn * 64 + i * 16 + l15) * 64 + coff0];
        }
#pragma unroll
        for (int im = 0; im < 4; ++im)
#pragma unroll
            for (int in = 0; in < 4; ++in)
                acc[im][in] = __builtin_amdgcn_mfma_f32_16x16x32_bf16(af[im], bfr[in], acc[im][in], 0, 0, 0);
#pragma unroll
        for (int i = 0; i < 4; ++i) {
            af[i]  = *(const bfrag_t*)&As[(wm * 64 + i * 16 + l15) * 64 + coff1];
            bfr[i] = *(const bfrag_t*)&Bs[(wn * 64 + i * 16 + l15) * 64 + coff1];
        }
#pragma unroll
        for (int im = 0; im < 4; ++im)
#pragma unroll
            for (int in = 0; in < 4; ++in)
                acc[im][in] = __builtin_amdgcn_mfma_f32_16x16x32_bf16(af[im], bfr[in], acc[im][in], 0, 0, 0);
        __syncthreads();
    }
    // coalesced store: y1c[b][m][hw], hw on l15
#pragma unroll
    for (int in = 0; in < 4; ++in) {
        const int n = n0 + wn * 64 + in * 16 + l15;
        const int b = n / HW, hw = n - b * HW;
#pragma unroll
        for (int im = 0; im < 4; ++im) {
#pragma unroll
            for (int r = 0; r < 4; ++r) {
                const int m = m0 + wm * 64 + im * 16 + (quad << 2) + r;
                float v = acc[im][in][r];
                v = v > 0.f ? v : 0.f;
                y1c[((size_t)(b * P1 + m)) * HW + hw] = f2bf(v);
            }
        }
    }
}

// ---------------- dconv: y2t[n][m] = relu(conv3x3(y1sp, wdb)) ----------------
// operands SWAPPED in mfma so D col(lane&15)=m -> m-contiguous stores
__global__ __launch_bounds__(256) void dconv_kernel(const unsigned short* __restrict__ y1sp,
                                                    const unsigned short* __restrict__ wdb,
                                                    unsigned short* __restrict__ y2t) {
    __shared__ __align__(16) unsigned short As[128 * 64];
    __shared__ __align__(16) unsigned short Bs[128 * 64];
    const int m0 = blockIdx.x * 128;
    const int n0 = blockIdx.y * 128;
    const int t = threadIdx.x;
    const int lane = t & 63, wave = t >> 6;
    const int l15 = lane & 15, quad = lane >> 4;
    const int wm = wave & 1, wn = wave >> 1;
    const int grow = lane >> 3;
    const int gsw  = ((lane & 7) ^ grow) << 3;
    const unsigned short* Asrc[4];
    const unsigned short* Bsrc[4];
    int ldso[4];
#pragma unroll
    for (int j = 0; j < 4; ++j) {
        int q = wave * 4 + j;
        int row = (q << 3) + grow;
        Asrc[j] = wdb + (size_t)(m0 + row) * P1 + gsw;
        int n = n0 + row;
        int b = n / HW, hw = n - b * HW;
        int h = hw / WIMG, w = hw - h * WIMG;
        Bsrc[j] = y1sp + ((size_t)b * PADHW + h * PADW + w) * P1 + gsw;  // top-left of 3x3 window
        ldso[j] = q * 512;
    }
    const int coff0 = ((quad)     ^ (l15 & 7)) << 3;
    const int coff1 = ((quad + 4) ^ (l15 & 7)) << 3;

    accvec_t acc[4][4];
    const accvec_t zero = {0.f, 0.f, 0.f, 0.f};
#pragma unroll
    for (int i = 0; i < 4; ++i)
#pragma unroll
        for (int j = 0; j < 4; ++j) acc[i][j] = zero;

    for (int r = 0; r < 9; ++r) {
        const int kh = r / 3, kw = r - kh * 3;
        const size_t aoff = (size_t)r * (P1 * P2);
        const int taboff = (kh * PADW + kw) * P1;
        for (int k0 = 0; k0 < P1; k0 += 64) {
#pragma unroll
            for (int j = 0; j < 4; ++j) {
                GLDS16(Asrc[j] + aoff + k0, &As[ldso[j]]);
                GLDS16(Bsrc[j] + taboff + k0, &Bs[ldso[j]]);
            }
            __syncthreads();
            bfrag_t af[4], bfr[4];
#pragma unroll
            for (int i = 0; i < 4; ++i) {
                af[i]  = *(const bfrag_t*)&As[(wm * 64 + i * 16 + l15) * 64 + coff0];
                bfr[i] = *(const bfrag_t*)&Bs[(wn * 64 + i * 16 + l15) * 64 + coff0];
            }
#pragma unroll
            for (int im = 0; im < 4; ++im)
#pragma unroll
                for (int in = 0; in < 4; ++in)
                    acc[im][in] = __builtin_amdgcn_mfma_f32_16x16x32_bf16(bfr[in], af[im], acc[im][in], 0, 0, 0);
#pragma unroll
            for (int i = 0; i < 4; ++i) {
                af[i]  = *(const bfrag_t*)&As[(wm * 64 + i * 16 + l15) * 64 + coff1];
                bfr[i] = *(const bfrag_t*)&Bs[(wn * 64 + i * 16 + l15) * 64 + coff1];
            }
#pragma unroll
            for (int im = 0; im < 4; ++im)
#pragma unroll
                for (int in = 0; in < 4; ++in)
                    acc[im][in] = __builtin_amdgcn_mfma_f32_16x16x32_bf16(bfr[in], af[im], acc[im][in], 0, 0, 0);
            __syncthreads();
        }
    }
    // swapped D mapping: col(l15)=m, row(quad*4+r)=n
#pragma unroll
    for (int im = 0; im < 4; ++im) {
        const int m = m0 + wm * 64 + im * 16 + l15;
#pragma unroll
        for (int in = 0; in < 4; ++in) {
#pragma unroll
            for (int r = 0; r < 4; ++r) {
                const int n = n0 + wn * 64 + in * 16 + (quad << 2) + r;
                float v = acc[im][in][r];
                v = v > 0.f ? v : 0.f;
                y2t[(size_t)n * P2 + m] = f2bf(v);
            }
        }
    }
}

// ---------------- conv3 + coalesced residual add + relu ----------------
__global__ __launch_bounds__(256) void conv3_kernel(const unsigned short* __restrict__ y2t,
                                                    const unsigned short* __restrict__ w3b,
                                                    const unsigned short* __restrict__ res,
                                                    float* __restrict__ out) {
    __shared__ __align__(16) unsigned short As[128 * 32];
    __shared__ __align__(16) unsigned short Bs[128 * 32];
    const int m0 = blockIdx.x * 128;
    const int n0 = blockIdx.y * 128;
    const int t = threadIdx.x;
    const int lane = t & 63, wave = t >> 6;
    const int l15 = lane & 15, quad = lane >> 4;
    const int wm = wave & 1, wn = wave >> 1;
    const int srow = lane >> 2, c8 = (lane & 3) << 3;
    const int row0 = wave * 32 + srow, row1 = row0 + 16;

    const unsigned short* a0 = w3b + (size_t)(m0 + row0) * P2 + c8;
    const unsigned short* a1 = w3b + (size_t)(m0 + row1) * P2 + c8;
    const unsigned short* b0 = y2t + (size_t)(n0 + row0) * P2 + c8;
    const unsigned short* b1 = y2t + (size_t)(n0 + row1) * P2 + c8;
    unsigned short* Ad0 = &As[(wave * 2 + 0) * 512];
    unsigned short* Ad1 = &As[(wave * 2 + 1) * 512];
    unsigned short* Bd0 = &Bs[(wave * 2 + 0) * 512];
    unsigned short* Bd1 = &Bs[(wave * 2 + 1) * 512];

    accvec_t acc[4][4];
    const accvec_t zero = {0.f, 0.f, 0.f, 0.f};
#pragma unroll
    for (int i = 0; i < 4; ++i)
#pragma unroll
        for (int j = 0; j < 4; ++j) acc[i][j] = zero;

    for (int k0 = 0; k0 < P2; k0 += 32) {
        GLDS16(a0 + k0, Ad0);
        GLDS16(a1 + k0, Ad1);
        GLDS16(b0 + k0, Bd0);
        GLDS16(b1 + k0, Bd1);
        __syncthreads();
        bfrag_t af[4], bfr[4];
#pragma unroll
        for (int i = 0; i < 4; ++i) {
            af[i]  = *(const bfrag_t*)&As[(wm * 64 + i * 16 + l15) * 32 + (quad << 3)];
            bfr[i] = *(const bfrag_t*)&Bs[(wn * 64 + i * 16 + l15) * 32 + (quad << 3)];
        }
#pragma unroll
        for (int im = 0; im < 4; ++im)
#pragma unroll
            for (int in = 0; in < 4; ++in)
                acc[im][in] = __builtin_amdgcn_mfma_f32_16x16x32_bf16(af[im], bfr[in], acc[im][in], 0, 0, 0);
        __syncthreads();
    }
#pragma unroll
    for (int in = 0; in < 4; ++in) {
        const int n = n0 + wn * 64 + in * 16 + l15;
        const int b = n / HW, hw = n - b * HW;
#pragma unroll
        for (int im = 0; im < 4; ++im) {
#pragma unroll
            for (int r = 0; r < 4; ++r) {
                const int m = m0 + wm * 64 + im * 16 + (quad << 2) + r;
                const size_t idx = ((size_t)(b * P3 + m)) * HW + hw;
                float v = acc[im][in][r] + bf2f(res[idx]);
                v = v > 0.f ? v : 0.f;
                out[idx] = v;
            }
        }
    }
}

extern "C" void kernel_launch(void* const* d_in, const int* in_sizes, int n_in,
                              void* d_out, int out_size, void* d_ws, size_t ws_size,
                              hipStream_t stream) {
    const float* x      = (const float*)d_in[0];
    const float* w1     = (const float*)d_in[1];
    const float* wd     = (const float*)d_in[2];
    const float* w3     = (const float*)d_in[3];
    const int*   perm_d = (const int*)d_in[4];
    const int*   perm_r = (const int*)d_in[5];
    float*       out    = (float*)d_out;

    char* ws = (char*)d_ws;
    unsigned short* y1sp  = (unsigned short*)(ws + 0);         // 14,745,600
    unsigned short* y2t   = (unsigned short*)(ws + 14745600);  // 12,845,056 (also y1c — dconv overwrites after shuffle_pad consumed it)
    int*            permT = (int*)(ws + 27590656);             //    802,816
    unsigned short* w1b   = (unsigned short*)(ws + 28393472);  //    524,288
    unsigned short* wdb   = (unsigned short*)(ws + 28917760);  //  1,179,648
    unsigned short* w3b   = (unsigned short*)(ws + 30097408);  //    524,288
    unsigned short* xt    = (unsigned short*)(ws + 30621696);  // 51,380,224 (also res — res_shuffle overwrites after conv1 consumed it)
    unsigned short* resb  = xt;
    unsigned short* y1c   = y2t;

    hipMemsetAsync(y1sp, 0, (size_t)BATCH * PADHW * P1 * sizeof(unsigned short), stream);
    permT_kernel<<<dim3(HW), dim3(256), 0, stream>>>(perm_d, permT);
    pack_weights_kernel<<<dim3(4352), dim3(256), 0, stream>>>(w1, wd, w3, w1b, wdb, w3b);
    transpose_x_kernel<<<dim3(16, 13, BATCH), dim3(256), 0, stream>>>(x, xt);

    conv1_kernel<<<dim3(P1 / 128, NFLAT / 128), dim3(256), 0, stream>>>(xt, w1b, y1c);
    res_shuffle_kernel<<<dim3(BATCH * CIN / 8), dim3(256), 0, stream>>>(x, perm_r, resb);
    shuffle_pad_kernel<<<dim3(BATCH * 8), dim3(256), 0, stream>>>(y1c, permT, y1sp);
    dconv_kernel<<<dim3(P2 / 128, NFLAT / 128), dim3(256), 0, stream>>>(y1sp, wdb, y2t);
    conv3_kernel<<<dim3(P3 / 128, NFLAT / 128), dim3(256), 0, stream>>>(y2t, w3b, resb, out);
}